// Round 18
// baseline (183.415 us; speedup 1.0000x reference)
//
#include <hip/hip_runtime.h>
#include <hip/hip_bf16.h>
#include <math.h>

#define N_NODES 50000
#define NE      100000
#define FDIM    768
#define NFUSE   3072
#define NB      256
#define NC      31

#define A1_CAP  16384
#define N1_CAP  4096
#define EB      ((NE + 255) / 256)        // 391
#define SCT     (2 * EB)                  // 782
#define GTN     12

#define TWT_BLOCKS  (8 * 576)
#define BIAS_BLOCKS 24
#define CVT_BLOCKS  512
#define MIX1_BLOCKS (SCT + TWT_BLOCKS + BIAS_BLOCKS + SCT)

// zero region: fA1(N) + fL1(N) + cnts(64) + dega(2*N1_CAP), in ints
#define ZERO_INTS (2 * N_NODES + 64 + 2 * N1_CAP)

typedef __hip_bfloat16 bf16;
typedef __attribute__((ext_vector_type(8))) short bf16x8;
typedef __attribute__((ext_vector_type(4))) float f32x4;

__device__ inline float u2f(unsigned short u) { return __uint_as_float(((unsigned int)u) << 16); }
__device__ inline unsigned short f2u(float f) { return __bfloat16_as_ushort(__float2bfloat16(f)); }

__device__ inline float aload_f(const float* p) {
    return __hip_atomic_load(p, __ATOMIC_RELAXED, __HIP_MEMORY_SCOPE_AGENT);
}
__device__ inline void astore_f(float* p, float v) {
    __hip_atomic_store(p, v, __ATOMIC_RELAXED, __HIP_MEMORY_SCOPE_AGENT);
}

__device__ inline void load_lds16(const void* g, void* l) {
    __builtin_amdgcn_global_load_lds(
        (const __attribute__((address_space(1))) void*)g,
        (__attribute__((address_space(3))) void*)l, 16, 0, 0);
}

// ---------------- fast zero (replaces slow rocclr small-fill) ----------------
__global__ __launch_bounds__(256) void zero_kernel(int4* __restrict__ dst) {
    const int i = blockIdx.x * 256 + threadIdx.x;
    const int n4 = (ZERO_INTS + 3) / 4;
    if (i < n4) dst[i] = make_int4(0, 0, 0, 0);
}

// ---------------- markA: gsi (mark+append+list0) + pass1 edges (bsearch gsi) ----------------
// cnts: 0=A1 count, 1=N1 count, 2=S0 count, 9=agghead done
__global__ __launch_bounds__(256) void markA_kernel(const int* __restrict__ gsi,
                                                    const int* __restrict__ src0,
                                                    const int* __restrict__ dst0,
                                                    const int* __restrict__ src1,
                                                    const int* __restrict__ dst1,
                                                    int* __restrict__ fL1,
                                                    int* __restrict__ fA1,
                                                    int* __restrict__ list1, int* __restrict__ idx1,
                                                    int* __restrict__ list2, int* __restrict__ idx2,
                                                    int* __restrict__ list0,
                                                    int* __restrict__ cnts) {
    const int t = threadIdx.x, b = blockIdx.x;
    if (b == 0) {
        const int n = gsi[t];
        if (atomicExch(&fL1[n], 1) == 0) {
            const int p = atomicAdd(&cnts[1], 1);
            if (p < N1_CAP) { list2[p] = n; idx2[n] = p; } else idx2[n] = 0;
        }
        if (atomicExch(&fA1[n], 1) == 0) {
            const int p = atomicAdd(&cnts[0], 1);
            if (p < A1_CAP) { list1[p] = n; idx1[n] = p; } else idx1[n] = 0;
        }
        const bool first = (t == 0) || (gsi[t - 1] != n);
        if (first) {
            const int p = atomicAdd(&cnts[2], 1);
            if (p < 256) list0[p] = n;
        }
        return;
    }
    __shared__ int g[256];
    g[t] = gsi[t];
    __syncthreads();
    const int eb = b - 1;
    const int r = (eb >= EB) ? 1 : 0;
    const int e = (eb - r * EB) * 256 + t;
    if (e >= NE) return;
    const int d = (r ? dst1 : dst0)[e];
    int lo = 0, hi = 256;
    while (lo < hi) { const int mid = (lo + hi) >> 1; if (g[mid] < d) lo = mid + 1; else hi = mid; }
    if (lo < 256 && g[lo] == d) {
        const int s = (r ? src1 : src0)[e];
        if (atomicExch(&fL1[s], 1) == 0) {
            const int p = atomicAdd(&cnts[1], 1);
            if (p < N1_CAP) { list2[p] = s; idx2[s] = p; } else idx2[s] = 0;
        }
        if (atomicExch(&fA1[s], 1) == 0) {
            const int p = atomicAdd(&cnts[0], 1);
            if (p < A1_CAP) { list1[p] = s; idx1[s] = p; } else idx1[s] = 0;
        }
    }
}

// ---------------- mix1: markB | twt8 | bias | hist ----------------
__global__ __launch_bounds__(256) void mix1_kernel(const int* __restrict__ src0,
                                                   const int* __restrict__ dst0,
                                                   const int* __restrict__ src1,
                                                   const int* __restrict__ dst1,
                                                   const int* __restrict__ fL1,
                                                   int* __restrict__ fA1,
                                                   int* __restrict__ list1, int* __restrict__ idx1,
                                                   int* __restrict__ cnts,
                                                   const float* __restrict__ w_sc,
                                                   const float* __restrict__ w_dc,
                                                   const float* __restrict__ w_scb,
                                                   const float* __restrict__ w_dcb,
                                                   const float* __restrict__ b_sc,
                                                   const float* __restrict__ b_dc,
                                                   const float* __restrict__ b_scb,
                                                   const float* __restrict__ b_dcb,
                                                   bf16* __restrict__ WtFl,
                                                   float* __restrict__ pb,
                                                   const int* __restrict__ idx2,
                                                   int* __restrict__ dega) {
    __shared__ float tile[32][33];
    const int b = blockIdx.x, t = threadIdx.x;
    if (b < SCT) {
        const int r = (b >= EB) ? 1 : 0;
        const int e = (b - r * EB) * 256 + t;
        if (e < NE && fL1[(r ? dst1 : dst0)[e]]) {
            const int s = (r ? src1 : src0)[e];
            if (atomicExch(&fA1[s], 1) == 0) {
                const int p = atomicAdd(&cnts[0], 1);
                if (p < A1_CAP) { list1[p] = s; idx1[s] = p; } else idx1[s] = 0;
            }
        }
    } else if (b < SCT + TWT_BLOCKS) {
        const int j = b - SCT;
        const int z = j / 576, cell = j % 576;
        const int l = z >> 2, sel2 = z & 3;
        const float* src;
        if (sel2 == 0) src = w_sc; else if (sel2 == 1) src = w_scb;
        else if (sel2 == 2) src = w_dc; else src = w_dcb;
        src += (size_t)l * FDIM * FDIM;
        bf16* dst = WtFl + (size_t)z * FDIM * FDIM;
        const int tx = t & 31, ty = t >> 5;
        const int x0 = (cell % 24) * 32, y0 = (cell / 24) * 32;
#pragma unroll
        for (int q = 0; q < 4; ++q)
            tile[ty + q * 8][tx] = src[(size_t)(y0 + ty + q * 8) * FDIM + x0 + tx];
        __syncthreads();
#pragma unroll
        for (int q = 0; q < 4; ++q)
            dst[(size_t)(x0 + ty + q * 8) * FDIM + y0 + tx] = __float2bfloat16(tile[tx][ty + q * 8]);
    } else if (b < SCT + TWT_BLOCKS + BIAS_BLOCKS) {
        const int idx = (b - SCT - TWT_BLOCKS) * 256 + t;
        const int l = idx / NFUSE, c = idx % NFUSE;
        const int sel2 = c / FDIM, off = c % FDIM;
        const float* src;
        if (sel2 == 0) src = b_sc; else if (sel2 == 1) src = b_scb;
        else if (sel2 == 2) src = b_dc; else src = b_dcb;
        pb[idx] = src[l * FDIM + off];
    } else {
        const int eb = b - SCT - TWT_BLOCKS - BIAS_BLOCKS;
        const int r = (eb >= EB) ? 1 : 0;
        const int e = (eb - r * EB) * 256 + t;
        if (e < NE) {
            const int d = (r ? dst1 : dst0)[e];
            if (fL1[d]) atomicAdd(&dega[r * N1_CAP + idx2[d]], 1);
        }
    }
}

// ---------------- mix2: scana (block 0) | cvt (blocks 1..512) ----------------
__global__ __launch_bounds__(256) void mix2_kernel(const int* __restrict__ dega,
                                                   int* __restrict__ rowpa,
                                                   int* __restrict__ cursora,
                                                   const float* __restrict__ feats,
                                                   const int* __restrict__ list1,
                                                   const int* __restrict__ pcnt,
                                                   bf16* __restrict__ h) {
    const int b = blockIdx.x, t = threadIdx.x;
    if (b == 0) {
        __shared__ int part[256];
        for (int r = 0; r < 2; ++r) {
            const int base = r * N1_CAP;
            int loc[16];
            int s = 0;
#pragma unroll
            for (int q = 0; q < 16; ++q) { loc[q] = dega[base + t * 16 + q]; s += loc[q]; }
            part[t] = s;
            __syncthreads();
            for (int o = 1; o < 256; o <<= 1) {
                int x = (t >= o) ? part[t - o] : 0;
                __syncthreads();
                part[t] += x;
                __syncthreads();
            }
            int run = part[t] - s;
            const int rbase = r * (N1_CAP + 1);
#pragma unroll
            for (int q = 0; q < 16; ++q) {
                rowpa[rbase + t * 16 + q] = run;
                cursora[base + t * 16 + q] = run;
                run += loc[q];
            }
            if (t == 255) rowpa[rbase + N1_CAP] = run;
            __syncthreads();
        }
        return;
    }
    int c = *pcnt; if (c > A1_CAP) c = A1_CAP;
    for (int i = b - 1; i < c; i += CVT_BLOCKS) {
        const int n = list1[i];
        const float* s = feats + (size_t)n * FDIM;
        bf16* d = h + (size_t)n * FDIM;
        for (int k = t; k < FDIM; k += 256) d[k] = __float2bfloat16(s[k]);
    }
}

// ---------------- two-job 128x128 MFMA GEMM, with optional scatter prologue ----------------
__global__ __launch_bounds__(256) void gemm2(const bf16* __restrict__ A,
                                             const bf16* __restrict__ Wt,
                                             const float* __restrict__ pb,
                                             bf16* __restrict__ C,
                                             const int* __restrict__ rlA,
                                             const int* __restrict__ cntAp, int capA,
                                             const int* __restrict__ rlB,
                                             const int* __restrict__ cntBp, int capB,
                                             const int* __restrict__ idxmap,
                                             int blocksA,
                                             int sct,
                                             const int* __restrict__ dst0,
                                             const int* __restrict__ dst1,
                                             const int* __restrict__ fL1,
                                             const int* __restrict__ idx2,
                                             int* __restrict__ cursora,
                                             int* __restrict__ eida) {
    int bid = blockIdx.x;
    if (bid < sct) {
        const int r = (bid >= EB) ? 1 : 0;
        const int e = (bid - r * EB) * 256 + threadIdx.x;
        if (e < NE) {
            const int d = (r ? dst1 : dst0)[e];
            if (fL1[d]) {
                const int p = atomicAdd(&cursora[r * N1_CAP + idx2[d]], 1);
                eida[(size_t)r * NE + p] = e;
            }
        }
        return;
    }
    bid -= sct;
    const int* rowlist;
    int cnt, col0;
    if (bid < blocksA) {
        rowlist = rlA; cnt = *cntAp; if (cnt > capA) cnt = capA; col0 = 0;
    } else {
        bid -= blocksA;
        rowlist = rlB; cnt = *cntBp; if (cnt > capB) cnt = capB; col0 = 1536;
    }
    const int tm = bid / GTN, tn = bid % GTN;
    const int m0 = tm * 128, n0 = tn * 128;
    if (m0 >= cnt) return;

    __shared__ __align__(16) short Abuf[128 * 64];
    __shared__ __align__(16) short Bbuf[128 * 64];
    const int t = threadIdx.x;
    const int wid = t >> 6, lane = t & 63;
    const int wr = wid >> 1, wc = wid & 1;
    const int lr = lane & 15, lk = lane >> 4;

    const f32x4 zero4 = {0.f, 0.f, 0.f, 0.f};
    f32x4 acc[4][4];
#pragma unroll
    for (int i = 0; i < 4; ++i)
#pragma unroll
        for (int j = 0; j < 4; ++j) acc[i][j] = zero4;

    int arow[4], brow[4], acol[4], ldsoff[4];
#pragma unroll
    for (int i = 0; i < 4; ++i) {
        const int s = i * 256 + t;
        const int rr = s >> 3, pch = s & 7;
        int ri = m0 + rr; if (ri >= cnt) ri = cnt - 1;
        arow[i] = rowlist[ri];
        brow[i] = col0 + n0 + rr;
        acol[i] = (pch ^ (rr & 7)) << 3;
        ldsoff[i] = (i * 256 + wid * 64) * 16;
    }

    for (int kt = 0; kt < FDIM / 64; ++kt) {
        const int k0 = kt * 64;
#pragma unroll
        for (int i = 0; i < 4; ++i) {
            load_lds16(A + (size_t)arow[i] * FDIM + k0 + acol[i], (char*)Abuf + ldsoff[i]);
            load_lds16(Wt + (size_t)brow[i] * FDIM + k0 + acol[i], (char*)Bbuf + ldsoff[i]);
        }
        __syncthreads();
#pragma unroll
        for (int kh = 0; kh < 2; ++kh) {
            bf16x8 av[4], bv[4];
            const int c = kh * 4 + lk;
#pragma unroll
            for (int i = 0; i < 4; ++i) {
                const int mm = wr * 64 + i * 16 + lr;
                av[i] = *(const bf16x8*)((const char*)Abuf + mm * 128 + ((c ^ (mm & 7)) << 4));
            }
#pragma unroll
            for (int j = 0; j < 4; ++j) {
                const int nn = wc * 64 + j * 16 + lr;
                bv[j] = *(const bf16x8*)((const char*)Bbuf + nn * 128 + ((c ^ (nn & 7)) << 4));
            }
#pragma unroll
            for (int i = 0; i < 4; ++i)
#pragma unroll
                for (int j = 0; j < 4; ++j)
                    acc[i][j] = __builtin_amdgcn_mfma_f32_16x16x32_bf16(bv[j], av[i], acc[i][j], 0, 0, 0);
        }
        __syncthreads();
    }

#pragma unroll
    for (int i = 0; i < 4; ++i) {
        const int row = m0 + wr * 64 + i * 16 + lr;
        if (row < cnt) {
            const int crow = idxmap[rowlist[row]];
#pragma unroll
            for (int j = 0; j < 4; ++j) {
                const int col = col0 + n0 + wc * 64 + j * 16 + lk * 4;
                const float4 b4 = *(const float4*)(pb + col);
                ushort4 w;
                w.x = f2u(acc[i][j][0] + b4.x);
                w.y = f2u(acc[i][j][1] + b4.y);
                w.z = f2u(acc[i][j][2] + b4.z);
                w.w = f2u(acc[i][j][3] + b4.w);
                *(ushort4*)(C + (size_t)crow * NFUSE + col) = w;
            }
        }
    }
}

// ---------------- online-softmax attention over an active-CSR row ----------------
__device__ inline void att_accum(const bf16* __restrict__ fsd, const int* __restrict__ idxsrc,
                                 int fdrow, int lane, const float* __restrict__ attn,
                                 int beg, int end,
                                 const int* __restrict__ eid, const int* __restrict__ src,
                                 int fs_off, int fd_off, float* __restrict__ out) {
    float fdv[12], atv[12];
    {
        const ushort4* pfd = (const ushort4*)(fsd + (size_t)fdrow * NFUSE + fd_off + lane * 12);
        const ushort4 d0 = pfd[0], d1 = pfd[1], d2 = pfd[2];
        fdv[0] = u2f(d0.x); fdv[1] = u2f(d0.y); fdv[2] = u2f(d0.z); fdv[3] = u2f(d0.w);
        fdv[4] = u2f(d1.x); fdv[5] = u2f(d1.y); fdv[6] = u2f(d1.z); fdv[7] = u2f(d1.w);
        fdv[8] = u2f(d2.x); fdv[9] = u2f(d2.y); fdv[10] = u2f(d2.z); fdv[11] = u2f(d2.w);
        const float4* pat = (const float4*)(attn + lane * 12);
        const float4 a0 = pat[0], a1 = pat[1], a2 = pat[2];
        atv[0] = a0.x; atv[1] = a0.y; atv[2] = a0.z; atv[3] = a0.w;
        atv[4] = a1.x; atv[5] = a1.y; atv[6] = a1.z; atv[7] = a1.w;
        atv[8] = a2.x; atv[9] = a2.y; atv[10] = a2.z; atv[11] = a2.w;
    }
    float m = -INFINITY, den = 0.f;
    float acc[12];
#pragma unroll
    for (int j = 0; j < 12; ++j) acc[j] = 0.f;

    for (int i = beg; i < end; ++i) {
        const int e = eid[i];
        const ushort4* pf = (const ushort4*)(fsd + (size_t)idxsrc[src[e]] * NFUSE + fs_off + lane * 12);
        const ushort4 a0 = pf[0], a1 = pf[1], a2 = pf[2];
        float fsv[12];
        fsv[0] = u2f(a0.x); fsv[1] = u2f(a0.y); fsv[2] = u2f(a0.z); fsv[3] = u2f(a0.w);
        fsv[4] = u2f(a1.x); fsv[5] = u2f(a1.y); fsv[6] = u2f(a1.z); fsv[7] = u2f(a1.w);
        fsv[8] = u2f(a2.x); fsv[9] = u2f(a2.y); fsv[10] = u2f(a2.z); fsv[11] = u2f(a2.w);
        float p = 0.f;
#pragma unroll
        for (int j = 0; j < 12; ++j) {
            float x = fsv[j] + fdv[j];
            x = (x > 0.f) ? x : 0.2f * x;
            p += x * atv[j];
        }
        p += __shfl_xor(p, 1);
        p += __shfl_xor(p, 2);
        p += __shfl_xor(p, 4);
        if (p > m) {
            const float sc = expf(m - p);
            den *= sc;
#pragma unroll
            for (int j = 0; j < 12; ++j) acc[j] *= sc;
            m = p;
        }
        const float w = expf(p - m);
        den += w;
#pragma unroll
        for (int j = 0; j < 12; ++j) acc[j] += w * fsv[j];
    }
    const float inv = (den > 0.f) ? 1.f / den : 0.f;
#pragma unroll
    for (int j = 0; j < 12; ++j) out[j] = acc[j] * inv;
}

// ---------------- layer-0 agg ----------------
__global__ __launch_bounds__(256) void aggL_kernel(const bf16* __restrict__ fsd,
                                                   const int* __restrict__ idx1,
                                                   const float* __restrict__ attn0,
                                                   const float* __restrict__ attn1,
                                                   const int* __restrict__ rowpa,
                                                   const int* __restrict__ eida,
                                                   const int* __restrict__ src0,
                                                   const int* __restrict__ src1,
                                                   bf16* __restrict__ h,
                                                   const int* __restrict__ list2,
                                                   const int* __restrict__ pcnt) {
    const int wid = threadIdx.x >> 6;
    const int lane = threadIdx.x & 63;
    int cnt = *pcnt; if (cnt > N1_CAP) cnt = N1_CAP;
    const int i = blockIdx.x * 4 + wid;
    if (i >= cnt) return;
    const int n = list2[i];
    const int fdrow = idx1[n];

    float a0[12], a1[12];
    att_accum(fsd, idx1, fdrow, lane, attn0, rowpa[i], rowpa[i + 1],
              eida, src0, 0, 1536, a0);
    att_accum(fsd, idx1, fdrow, lane, attn1, rowpa[(N1_CAP + 1) + i], rowpa[(N1_CAP + 1) + i + 1],
              eida + NE, src1, 768, 2304, a1);

    const size_t base = (size_t)n * FDIM + lane * 12;
    const ushort4* ph = (const ushort4*)(h + base);
    const ushort4 h0 = ph[0], h1 = ph[1], h2 = ph[2];
    ushort4 r0, r1, r2;
    r0.x = f2u(u2f(h0.x) + a0[0] + a1[0]);  r0.y = f2u(u2f(h0.y) + a0[1] + a1[1]);
    r0.z = f2u(u2f(h0.z) + a0[2] + a1[2]);  r0.w = f2u(u2f(h0.w) + a0[3] + a1[3]);
    r1.x = f2u(u2f(h1.x) + a0[4] + a1[4]);  r1.y = f2u(u2f(h1.y) + a0[5] + a1[5]);
    r1.z = f2u(u2f(h1.z) + a0[6] + a1[6]);  r1.w = f2u(u2f(h1.w) + a0[7] + a1[7]);
    r2.x = f2u(u2f(h2.x) + a0[8] + a1[8]);  r2.y = f2u(u2f(h2.y) + a0[9] + a1[9]);
    r2.z = f2u(u2f(h2.z) + a0[10] + a1[10]); r2.w = f2u(u2f(h2.w) + a0[11] + a1[11]);
    ((ushort4*)(h + base))[0] = r0; ((ushort4*)(h + base))[1] = r1; ((ushort4*)(h + base))[2] = r2;
}

// ---------------- fused layer-1 agg + MLP head + last-block loss ----------------
__global__ __launch_bounds__(256) void agghead_kernel(const bf16* __restrict__ fsd,
                                                      const int* __restrict__ idx2,
                                                      const float* __restrict__ attn0,
                                                      const float* __restrict__ attn1,
                                                      const int* __restrict__ rowpa,
                                                      const int* __restrict__ eida,
                                                      const int* __restrict__ src0,
                                                      const int* __restrict__ src1,
                                                      const bf16* __restrict__ h,
                                                      const int* __restrict__ gsi,
                                                      const float* __restrict__ fc1w,
                                                      const float* __restrict__ fc1b,
                                                      const float* __restrict__ fc2w,
                                                      const float* __restrict__ fc2b,
                                                      const int* __restrict__ labels,
                                                      int* __restrict__ cnts,
                                                      float* __restrict__ out) {
    __shared__ float a0s[FDIM], a1s[FDIM], fe[FDIM];
    __shared__ float hid[256];
    const int b = blockIdx.x, t = threadIdx.x;
    const int n = gsi[b];
    const int wv = t >> 6, lane = t & 63;
    if (wv < 2) {
        const int j = idx2[n];
        const int rb = wv * (N1_CAP + 1);
        float v[12];
        att_accum(fsd, idx2, j, lane, wv ? attn1 : attn0,
                  rowpa[rb + j], rowpa[rb + j + 1],
                  eida + (size_t)wv * NE, wv ? src1 : src0,
                  wv ? 768 : 0, wv ? 2304 : 1536, v);
        float* dl = wv ? a1s : a0s;
#pragma unroll
        for (int q = 0; q < 12; ++q) dl[lane * 12 + q] = v[q];
    }
    __syncthreads();
    for (int d = t; d < FDIM; d += 256)
        fe[d] = u2f(__bfloat16_as_ushort(h[(size_t)n * FDIM + d])) + a0s[d] + a1s[d];
    __syncthreads();
    float acc = fc1b[t];
    for (int k = 0; k < FDIM; ++k) acc += fe[k] * fc1w[k * 256 + t];
    hid[t] = (acc > 0.f) ? acc : 0.f;
    __syncthreads();
    if (t < NC) {
        float a2 = fc2b[t];
        for (int k = 0; k < 256; ++k) a2 += hid[k] * fc2w[k * NC + t];
        astore_f(&out[1 + b * NC + t], a2);
    }

    __syncthreads();
    __shared__ int amlast;
    if (t == 0) amlast = (atomicAdd(&cnts[9], 1) == NB - 1) ? 1 : 0;
    __syncthreads();
    if (amlast) {
        __shared__ float red[256];
        float m = -INFINITY;
        float lg[NC];
#pragma unroll
        for (int c = 0; c < NC; ++c) {
            lg[c] = aload_f(&out[1 + t * NC + c]);
            m = fmaxf(m, lg[c]);
        }
        float sum = 0.f;
#pragma unroll
        for (int c = 0; c < NC; ++c) sum += expf(lg[c] - m);
        const float lse = m + logf(sum);
        const float ll = lg[labels[t]];
        red[t] = lse - ll;
        __syncthreads();
        for (int s = 128; s > 0; s >>= 1) {
            if (t < s) red[t] += red[t + s];
            __syncthreads();
        }
        if (t == 0) out[0] = red[0] / (float)NB;
    }
}

extern "C" void kernel_launch(void* const* d_in, const int* in_sizes, int n_in,
                              void* d_out, int out_size, void* d_ws, size_t ws_size,
                              hipStream_t stream) {
    const float* feats = (const float*)d_in[0];
    const int* src0    = (const int*)d_in[15];
    const int* dst0    = (const int*)d_in[16];
    const int* src1    = (const int*)d_in[17];
    const int* dst1    = (const int*)d_in[18];
    const int* gsi     = (const int*)d_in[19];
    const int* labels  = (const int*)d_in[20];

    const size_t NF = (size_t)N_NODES * FDIM;
    const size_t WSZ = (size_t)FDIM * FDIM;
    char* p = (char*)d_ws;
    bf16* h    = (bf16*)p;  p += NF * 2;
    bf16* fsd  = (bf16*)p;  p += (size_t)A1_CAP * NFUSE * 2;
    bf16* WtFl = (bf16*)p;  p += 8 * WSZ * 2;
    float* pb  = (float*)p; p += 2 * NFUSE * 4;
    int* fA1  = (int*)p;    p += (size_t)N_NODES * 4;
    int* fL1  = (int*)p;    p += (size_t)N_NODES * 4;
    int* cnts = (int*)p;    p += 64 * 4;
    int* dega = (int*)p;    p += 2 * (size_t)N1_CAP * 4;
    int* idx1  = (int*)p;   p += (size_t)N_NODES * 4;
    int* idx2  = (int*)p;   p += (size_t)N_NODES * 4;
    int* list1 = (int*)p;   p += (size_t)A1_CAP * 4;
    int* list2 = (int*)p;   p += (size_t)N1_CAP * 4;
    int* list0 = (int*)p;   p += 256 * 4;
    int* rowpa = (int*)p;   p += 2 * ((size_t)N1_CAP + 1) * 4;
    int* cursora = (int*)p; p += 2 * (size_t)N1_CAP * 4;
    int* eida  = (int*)p;   p += 2 * (size_t)NE * 4;

    // 1. zero flags/cnts/dega with our own kernel (rocclr small-fill runs at ~5 GB/s)
    zero_kernel<<<(ZERO_INTS / 4 + 255) / 256, 256, 0, stream>>>((int4*)fA1);
    // 2. markA  (fL1/idx2/list2 FINAL after this)
    markA_kernel<<<1 + SCT, 256, 0, stream>>>(gsi, src0, dst0, src1, dst1,
                                              fL1, fA1, list1, idx1, list2, idx2, list0, cnts);
    // 3. mix1: markB | twt | bias | hist
    mix1_kernel<<<MIX1_BLOCKS, 256, 0, stream>>>(
        src0, dst0, src1, dst1, fL1, fA1, list1, idx1, cnts,
        (const float*)d_in[1], (const float*)d_in[3], (const float*)d_in[6], (const float*)d_in[8],
        (const float*)d_in[2], (const float*)d_in[4], (const float*)d_in[7], (const float*)d_in[9],
        WtFl, pb, idx2, dega);
    // 4. mix2: scana | cvt
    mix2_kernel<<<1 + CVT_BLOCKS, 256, 0, stream>>>(dega, rowpa, cursora,
                                                    feats, list1, &cnts[0], h);

    const int blocksA0 = (A1_CAP / 128) * GTN;
    const int blocksB0 = (N1_CAP / 128) * GTN;
    const int blocksA1 = (N1_CAP / 128) * GTN;
    const int blocksB1 = (256 / 128) * GTN;

    // 5. scatter + layer-0 GEMM
    gemm2<<<SCT + blocksA0 + blocksB0, 256, 0, stream>>>(
        h, WtFl, pb, fsd,
        list1, &cnts[0], A1_CAP, list2, &cnts[1], N1_CAP, idx1, blocksA0,
        SCT, dst0, dst1, fL1, idx2, cursora, eida);
    // 6. layer-0 agg
    aggL_kernel<<<(N1_CAP + 3) / 4, 256, 0, stream>>>(
        fsd, idx1, (const float*)d_in[5], (const float*)d_in[10],
        rowpa, eida, src0, src1, h, list2, &cnts[1]);
    // 7. layer-1 GEMM
    gemm2<<<blocksA1 + blocksB1, 256, 0, stream>>>(
        h, WtFl + 4 * WSZ, pb + NFUSE, fsd,
        list2, &cnts[1], N1_CAP, list0, &cnts[2], 256, idx2, blocksA1,
        0, dst0, dst1, fL1, idx2, cursora, eida);
    // 8. layer-1 agg + head + last-block loss
    agghead_kernel<<<NB, 256, 0, stream>>>(
        fsd, idx2, (const float*)d_in[5] + FDIM, (const float*)d_in[10] + FDIM,
        rowpa, eida, src0, src1, h, gsi,
        (const float*)d_in[11], (const float*)d_in[12],
        (const float*)d_in[13], (const float*)d_in[14],
        labels, cnts, (float*)d_out);
}

// Round 19
// 163.058 us; speedup vs baseline: 1.1248x; 1.1248x over previous
//
#include <hip/hip_runtime.h>
#include <hip/hip_bf16.h>
#include <math.h>

#define N_NODES 50000
#define NE      100000
#define FDIM    768
#define NFUSE   3072
#define NB      256
#define NC      31

#define A1_CAP  16384
#define N1_CAP  4096
#define NBLK    ((N_NODES + 255) / 256)   // 196
#define EB      ((NE + 255) / 256)        // 391
#define SCT     (2 * EB)                  // 782
#define GTN     12

#define TWT_BLOCKS  (8 * 576)
#define BIAS_BLOCKS 24
#define CVT_BLOCKS  512
#define SETUP_BLOCKS (TWT_BLOCKS + BIAS_BLOCKS + CVT_BLOCKS)
#define SETUPH_BLOCKS (SETUP_BLOCKS + SCT)

// zero region: fA1(N) + fL1(N) + cnts(64) + dega(2*N1_CAP), in ints
#define ZERO_INTS (2 * N_NODES + 64 + 2 * N1_CAP)

typedef __hip_bfloat16 bf16;
typedef __attribute__((ext_vector_type(8))) short bf16x8;
typedef __attribute__((ext_vector_type(4))) float f32x4;

__device__ inline float u2f(unsigned short u) { return __uint_as_float(((unsigned int)u) << 16); }
__device__ inline unsigned short f2u(float f) { return __bfloat16_as_ushort(__float2bfloat16(f)); }

__device__ inline float aload_f(const float* p) {
    return __hip_atomic_load(p, __ATOMIC_RELAXED, __HIP_MEMORY_SCOPE_AGENT);
}
__device__ inline void astore_f(float* p, float v) {
    __hip_atomic_store(p, v, __ATOMIC_RELAXED, __HIP_MEMORY_SCOPE_AGENT);
}

__device__ inline void load_lds16(const void* g, void* l) {
    __builtin_amdgcn_global_load_lds(
        (const __attribute__((address_space(1))) void*)g,
        (__attribute__((address_space(3))) void*)l, 16, 0, 0);
}

// ---------------- fast zero ----------------
__global__ __launch_bounds__(256) void zero_kernel(int4* __restrict__ dst) {
    const int i = blockIdx.x * 256 + threadIdx.x;
    const int n4 = (ZERO_INTS + 3) / 4;
    if (i < n4) dst[i] = make_int4(0, 0, 0, 0);
}

// ---------------- markA: gsi marks+list0 + pass1 edges (bsearch gsi), plain stores ----------------
// cnts: 0=A1 count, 1=N1 count, 2=S0 count, 9=agghead done
__global__ __launch_bounds__(256) void markA_kernel(const int* __restrict__ gsi,
                                                    const int* __restrict__ src0,
                                                    const int* __restrict__ dst0,
                                                    const int* __restrict__ src1,
                                                    const int* __restrict__ dst1,
                                                    int* __restrict__ fL1,
                                                    int* __restrict__ fA1,
                                                    int* __restrict__ list0,
                                                    int* __restrict__ cnts) {
    const int t = threadIdx.x, b = blockIdx.x;
    if (b == 0) {
        const int n = gsi[t];
        fL1[n] = 1; fA1[n] = 1;
        const bool first = (t == 0) || (gsi[t - 1] != n);
        if (first) {
            const int p = atomicAdd(&cnts[2], 1);
            if (p < 256) list0[p] = n;
        }
        return;
    }
    __shared__ int g[256];
    g[t] = gsi[t];
    __syncthreads();
    const int eb = b - 1;
    const int r = (eb >= EB) ? 1 : 0;
    const int e = (eb - r * EB) * 256 + t;
    if (e >= NE) return;
    const int d = (r ? dst1 : dst0)[e];
    int lo = 0, hi = 256;
    while (lo < hi) { const int mid = (lo + hi) >> 1; if (g[mid] < d) lo = mid + 1; else hi = mid; }
    if (lo < 256 && g[lo] == d) {
        const int s = (r ? src1 : src0)[e];
        fL1[s] = 1; fA1[s] = 1;
    }
}

// ---------------- markB: pass2 (dst in fL1 -> fA1[src]=1) ----------------
__global__ __launch_bounds__(256) void markB_kernel(const int* __restrict__ src0,
                                                    const int* __restrict__ dst0,
                                                    const int* __restrict__ src1,
                                                    const int* __restrict__ dst1,
                                                    const int* __restrict__ fL1,
                                                    int* __restrict__ fA1) {
    const int e = blockIdx.x * 256 + threadIdx.x;
    if (e >= NE) return;
    const int r = blockIdx.y;
    if (fL1[(r ? dst1 : dst0)[e]]) fA1[(r ? src1 : src0)[e]] = 1;
}

// ---------------- compact ----------------
__global__ __launch_bounds__(256) void compact_kernel(const int* __restrict__ fA1,
                                                      const int* __restrict__ fL1,
                                                      int* __restrict__ list1, int* __restrict__ idx1,
                                                      int* __restrict__ list2, int* __restrict__ idx2,
                                                      int* __restrict__ cnts) {
    const int n = blockIdx.x * 256 + threadIdx.x;
    if (n >= N_NODES) return;
    if (fA1[n]) {
        const int p = atomicAdd(&cnts[0], 1);
        if (p < A1_CAP) { list1[p] = n; idx1[n] = p; } else idx1[n] = 0;
    }
    if (fL1[n]) {
        const int p = atomicAdd(&cnts[1], 1);
        if (p < N1_CAP) { list2[p] = n; idx2[n] = p; } else idx2[n] = 0;
    }
}

// ---------------- setup: twt8 | bias | cvt | hist (all overlap; lists final) ----------------
__global__ __launch_bounds__(256) void setup_kernel(const float* __restrict__ w_sc,
                                                    const float* __restrict__ w_dc,
                                                    const float* __restrict__ w_scb,
                                                    const float* __restrict__ w_dcb,
                                                    const float* __restrict__ b_sc,
                                                    const float* __restrict__ b_dc,
                                                    const float* __restrict__ b_scb,
                                                    const float* __restrict__ b_dcb,
                                                    const float* __restrict__ feats,
                                                    const int* __restrict__ list,
                                                    const int* __restrict__ pcnt,
                                                    bf16* __restrict__ WtFl,
                                                    float* __restrict__ pb,
                                                    bf16* __restrict__ h,
                                                    const int* __restrict__ dst0,
                                                    const int* __restrict__ dst1,
                                                    const int* __restrict__ fL1,
                                                    const int* __restrict__ idx2,
                                                    int* __restrict__ dega) {
    __shared__ float tile[32][33];
    const int b = blockIdx.x;
    const int t = threadIdx.x;
    if (b < TWT_BLOCKS) {
        const int z = b / 576, cell = b % 576;
        const int l = z >> 2, sel2 = z & 3;
        const float* src;
        if (sel2 == 0) src = w_sc; else if (sel2 == 1) src = w_scb;
        else if (sel2 == 2) src = w_dc; else src = w_dcb;
        src += (size_t)l * FDIM * FDIM;
        bf16* dst = WtFl + (size_t)z * FDIM * FDIM;
        const int tx = t & 31, ty = t >> 5;
        const int x0 = (cell % 24) * 32, y0 = (cell / 24) * 32;
#pragma unroll
        for (int q = 0; q < 4; ++q)
            tile[ty + q * 8][tx] = src[(size_t)(y0 + ty + q * 8) * FDIM + x0 + tx];
        __syncthreads();
#pragma unroll
        for (int q = 0; q < 4; ++q)
            dst[(size_t)(x0 + ty + q * 8) * FDIM + y0 + tx] = __float2bfloat16(tile[tx][ty + q * 8]);
    } else if (b < TWT_BLOCKS + BIAS_BLOCKS) {
        const int idx = (b - TWT_BLOCKS) * 256 + t;
        const int l = idx / NFUSE, c = idx % NFUSE;
        const int sel2 = c / FDIM, off = c % FDIM;
        const float* src;
        if (sel2 == 0) src = b_sc; else if (sel2 == 1) src = b_scb;
        else if (sel2 == 2) src = b_dc; else src = b_dcb;
        pb[idx] = src[l * FDIM + off];
    } else if (b < SETUP_BLOCKS) {
        int c = *pcnt; if (c > A1_CAP) c = A1_CAP;
        for (int i = b - TWT_BLOCKS - BIAS_BLOCKS; i < c; i += CVT_BLOCKS) {
            const int n = list[i];
            const float* s = feats + (size_t)n * FDIM;
            bf16* d = h + (size_t)n * FDIM;
            for (int k = t; k < FDIM; k += 256) d[k] = __float2bfloat16(s[k]);
        }
    } else {
        const int eb = b - SETUP_BLOCKS;
        const int r = (eb >= EB) ? 1 : 0;
        const int e = (eb - r * EB) * 256 + t;
        if (e < NE) {
            const int d = (r ? dst1 : dst0)[e];
            if (fL1[d]) atomicAdd(&dega[r * N1_CAP + idx2[d]], 1);
        }
    }
}

// ---------------- active scan (1 block) ----------------
__global__ __launch_bounds__(256) void scana_kernel(const int* __restrict__ dega,
                                                    int* __restrict__ rowpa,
                                                    int* __restrict__ cursora) {
    __shared__ int part[256];
    const int t = threadIdx.x;
    for (int r = 0; r < 2; ++r) {
        const int base = r * N1_CAP;
        int loc[16];
        int s = 0;
#pragma unroll
        for (int q = 0; q < 16; ++q) { loc[q] = dega[base + t * 16 + q]; s += loc[q]; }
        part[t] = s;
        __syncthreads();
        for (int o = 1; o < 256; o <<= 1) {
            int x = (t >= o) ? part[t - o] : 0;
            __syncthreads();
            part[t] += x;
            __syncthreads();
        }
        int run = part[t] - s;
        const int rbase = r * (N1_CAP + 1);
#pragma unroll
        for (int q = 0; q < 16; ++q) {
            rowpa[rbase + t * 16 + q] = run;
            cursora[base + t * 16 + q] = run;
            run += loc[q];
        }
        if (t == 255) rowpa[rbase + N1_CAP] = run;
        __syncthreads();
    }
}

// ---------------- active scatter ----------------
__global__ __launch_bounds__(256) void scattera_kernel(const int* __restrict__ dst0,
                                                       const int* __restrict__ dst1,
                                                       const int* __restrict__ fL1,
                                                       const int* __restrict__ idx2,
                                                       int* __restrict__ cursora,
                                                       int* __restrict__ eida) {
    const int e = blockIdx.x * 256 + threadIdx.x;
    if (e >= NE) return;
    const int r = blockIdx.y;
    const int d = (r ? dst1 : dst0)[e];
    if (fL1[d]) {
        const int p = atomicAdd(&cursora[r * N1_CAP + idx2[d]], 1);
        eida[(size_t)r * NE + p] = e;
    }
}

// ---------------- two-job 128x128 MFMA GEMM ----------------
__global__ __launch_bounds__(256) void gemm2(const bf16* __restrict__ A,
                                             const bf16* __restrict__ Wt,
                                             const float* __restrict__ pb,
                                             bf16* __restrict__ C,
                                             const int* __restrict__ rlA,
                                             const int* __restrict__ cntAp, int capA,
                                             const int* __restrict__ rlB,
                                             const int* __restrict__ cntBp, int capB,
                                             const int* __restrict__ idxmap,
                                             int blocksA) {
    int bid = blockIdx.x;
    const int* rowlist;
    int cnt, col0;
    if (bid < blocksA) {
        rowlist = rlA; cnt = *cntAp; if (cnt > capA) cnt = capA; col0 = 0;
    } else {
        bid -= blocksA;
        rowlist = rlB; cnt = *cntBp; if (cnt > capB) cnt = capB; col0 = 1536;
    }
    const int tm = bid / GTN, tn = bid % GTN;
    const int m0 = tm * 128, n0 = tn * 128;
    if (m0 >= cnt) return;

    __shared__ __align__(16) short Abuf[128 * 64];
    __shared__ __align__(16) short Bbuf[128 * 64];
    const int t = threadIdx.x;
    const int wid = t >> 6, lane = t & 63;
    const int wr = wid >> 1, wc = wid & 1;
    const int lr = lane & 15, lk = lane >> 4;

    const f32x4 zero4 = {0.f, 0.f, 0.f, 0.f};
    f32x4 acc[4][4];
#pragma unroll
    for (int i = 0; i < 4; ++i)
#pragma unroll
        for (int j = 0; j < 4; ++j) acc[i][j] = zero4;

    int arow[4], brow[4], acol[4], ldsoff[4];
#pragma unroll
    for (int i = 0; i < 4; ++i) {
        const int s = i * 256 + t;
        const int rr = s >> 3, pch = s & 7;
        int ri = m0 + rr; if (ri >= cnt) ri = cnt - 1;
        arow[i] = rowlist[ri];
        brow[i] = col0 + n0 + rr;
        acol[i] = (pch ^ (rr & 7)) << 3;
        ldsoff[i] = (i * 256 + wid * 64) * 16;
    }

    for (int kt = 0; kt < FDIM / 64; ++kt) {
        const int k0 = kt * 64;
#pragma unroll
        for (int i = 0; i < 4; ++i) {
            load_lds16(A + (size_t)arow[i] * FDIM + k0 + acol[i], (char*)Abuf + ldsoff[i]);
            load_lds16(Wt + (size_t)brow[i] * FDIM + k0 + acol[i], (char*)Bbuf + ldsoff[i]);
        }
        __syncthreads();
#pragma unroll
        for (int kh = 0; kh < 2; ++kh) {
            bf16x8 av[4], bv[4];
            const int c = kh * 4 + lk;
#pragma unroll
            for (int i = 0; i < 4; ++i) {
                const int mm = wr * 64 + i * 16 + lr;
                av[i] = *(const bf16x8*)((const char*)Abuf + mm * 128 + ((c ^ (mm & 7)) << 4));
            }
#pragma unroll
            for (int j = 0; j < 4; ++j) {
                const int nn = wc * 64 + j * 16 + lr;
                bv[j] = *(const bf16x8*)((const char*)Bbuf + nn * 128 + ((c ^ (nn & 7)) << 4));
            }
#pragma unroll
            for (int i = 0; i < 4; ++i)
#pragma unroll
                for (int j = 0; j < 4; ++j)
                    acc[i][j] = __builtin_amdgcn_mfma_f32_16x16x32_bf16(bv[j], av[i], acc[i][j], 0, 0, 0);
        }
        __syncthreads();
    }

#pragma unroll
    for (int i = 0; i < 4; ++i) {
        const int row = m0 + wr * 64 + i * 16 + lr;
        if (row < cnt) {
            const int crow = idxmap[rowlist[row]];
#pragma unroll
            for (int j = 0; j < 4; ++j) {
                const int col = col0 + n0 + wc * 64 + j * 16 + lk * 4;
                const float4 b4 = *(const float4*)(pb + col);
                ushort4 w;
                w.x = f2u(acc[i][j][0] + b4.x);
                w.y = f2u(acc[i][j][1] + b4.y);
                w.z = f2u(acc[i][j][2] + b4.z);
                w.w = f2u(acc[i][j][3] + b4.w);
                *(ushort4*)(C + (size_t)crow * NFUSE + col) = w;
            }
        }
    }
}

// ---------------- online-softmax attention over an active-CSR row ----------------
__device__ inline void att_accum(const bf16* __restrict__ fsd, const int* __restrict__ idxsrc,
                                 int fdrow, int lane, const float* __restrict__ attn,
                                 int beg, int end,
                                 const int* __restrict__ eid, const int* __restrict__ src,
                                 int fs_off, int fd_off, float* __restrict__ out) {
    float fdv[12], atv[12];
    {
        const ushort4* pfd = (const ushort4*)(fsd + (size_t)fdrow * NFUSE + fd_off + lane * 12);
        const ushort4 d0 = pfd[0], d1 = pfd[1], d2 = pfd[2];
        fdv[0] = u2f(d0.x); fdv[1] = u2f(d0.y); fdv[2] = u2f(d0.z); fdv[3] = u2f(d0.w);
        fdv[4] = u2f(d1.x); fdv[5] = u2f(d1.y); fdv[6] = u2f(d1.z); fdv[7] = u2f(d1.w);
        fdv[8] = u2f(d2.x); fdv[9] = u2f(d2.y); fdv[10] = u2f(d2.z); fdv[11] = u2f(d2.w);
        const float4* pat = (const float4*)(attn + lane * 12);
        const float4 a0 = pat[0], a1 = pat[1], a2 = pat[2];
        atv[0] = a0.x; atv[1] = a0.y; atv[2] = a0.z; atv[3] = a0.w;
        atv[4] = a1.x; atv[5] = a1.y; atv[6] = a1.z; atv[7] = a1.w;
        atv[8] = a2.x; atv[9] = a2.y; atv[10] = a2.z; atv[11] = a2.w;
    }
    float m = -INFINITY, den = 0.f;
    float acc[12];
#pragma unroll
    for (int j = 0; j < 12; ++j) acc[j] = 0.f;

    for (int i = beg; i < end; ++i) {
        const int e = eid[i];
        const ushort4* pf = (const ushort4*)(fsd + (size_t)idxsrc[src[e]] * NFUSE + fs_off + lane * 12);
        const ushort4 a0 = pf[0], a1 = pf[1], a2 = pf[2];
        float fsv[12];
        fsv[0] = u2f(a0.x); fsv[1] = u2f(a0.y); fsv[2] = u2f(a0.z); fsv[3] = u2f(a0.w);
        fsv[4] = u2f(a1.x); fsv[5] = u2f(a1.y); fsv[6] = u2f(a1.z); fsv[7] = u2f(a1.w);
        fsv[8] = u2f(a2.x); fsv[9] = u2f(a2.y); fsv[10] = u2f(a2.z); fsv[11] = u2f(a2.w);
        float p = 0.f;
#pragma unroll
        for (int j = 0; j < 12; ++j) {
            float x = fsv[j] + fdv[j];
            x = (x > 0.f) ? x : 0.2f * x;
            p += x * atv[j];
        }
        p += __shfl_xor(p, 1);
        p += __shfl_xor(p, 2);
        p += __shfl_xor(p, 4);
        if (p > m) {
            const float sc = expf(m - p);
            den *= sc;
#pragma unroll
            for (int j = 0; j < 12; ++j) acc[j] *= sc;
            m = p;
        }
        const float w = expf(p - m);
        den += w;
#pragma unroll
        for (int j = 0; j < 12; ++j) acc[j] += w * fsv[j];
    }
    const float inv = (den > 0.f) ? 1.f / den : 0.f;
#pragma unroll
    for (int j = 0; j < 12; ++j) out[j] = acc[j] * inv;
}

// ---------------- layer-0 agg ----------------
__global__ __launch_bounds__(256) void aggL_kernel(const bf16* __restrict__ fsd,
                                                   const int* __restrict__ idx1,
                                                   const float* __restrict__ attn0,
                                                   const float* __restrict__ attn1,
                                                   const int* __restrict__ rowpa,
                                                   const int* __restrict__ eida,
                                                   const int* __restrict__ src0,
                                                   const int* __restrict__ src1,
                                                   bf16* __restrict__ h,
                                                   const int* __restrict__ list2,
                                                   const int* __restrict__ pcnt) {
    const int wid = threadIdx.x >> 6;
    const int lane = threadIdx.x & 63;
    int cnt = *pcnt; if (cnt > N1_CAP) cnt = N1_CAP;
    const int i = blockIdx.x * 4 + wid;
    if (i >= cnt) return;
    const int n = list2[i];
    const int fdrow = idx1[n];

    float a0[12], a1[12];
    att_accum(fsd, idx1, fdrow, lane, attn0, rowpa[i], rowpa[i + 1],
              eida, src0, 0, 1536, a0);
    att_accum(fsd, idx1, fdrow, lane, attn1, rowpa[(N1_CAP + 1) + i], rowpa[(N1_CAP + 1) + i + 1],
              eida + NE, src1, 768, 2304, a1);

    const size_t base = (size_t)n * FDIM + lane * 12;
    const ushort4* ph = (const ushort4*)(h + base);
    const ushort4 h0 = ph[0], h1 = ph[1], h2 = ph[2];
    ushort4 r0, r1, r2;
    r0.x = f2u(u2f(h0.x) + a0[0] + a1[0]);  r0.y = f2u(u2f(h0.y) + a0[1] + a1[1]);
    r0.z = f2u(u2f(h0.z) + a0[2] + a1[2]);  r0.w = f2u(u2f(h0.w) + a0[3] + a1[3]);
    r1.x = f2u(u2f(h1.x) + a0[4] + a1[4]);  r1.y = f2u(u2f(h1.y) + a0[5] + a1[5]);
    r1.z = f2u(u2f(h1.z) + a0[6] + a1[6]);  r1.w = f2u(u2f(h1.w) + a0[7] + a1[7]);
    r2.x = f2u(u2f(h2.x) + a0[8] + a1[8]);  r2.y = f2u(u2f(h2.y) + a0[9] + a1[9]);
    r2.z = f2u(u2f(h2.z) + a0[10] + a1[10]); r2.w = f2u(u2f(h2.w) + a0[11] + a1[11]);
    ((ushort4*)(h + base))[0] = r0; ((ushort4*)(h + base))[1] = r1; ((ushort4*)(h + base))[2] = r2;
}

// ---------------- fused layer-1 agg + MLP head + last-block loss ----------------
__global__ __launch_bounds__(256) void agghead_kernel(const bf16* __restrict__ fsd,
                                                      const int* __restrict__ idx2,
                                                      const float* __restrict__ attn0,
                                                      const float* __restrict__ attn1,
                                                      const int* __restrict__ rowpa,
                                                      const int* __restrict__ eida,
                                                      const int* __restrict__ src0,
                                                      const int* __restrict__ src1,
                                                      const bf16* __restrict__ h,
                                                      const int* __restrict__ gsi,
                                                      const float* __restrict__ fc1w,
                                                      const float* __restrict__ fc1b,
                                                      const float* __restrict__ fc2w,
                                                      const float* __restrict__ fc2b,
                                                      const int* __restrict__ labels,
                                                      int* __restrict__ cnts,
                                                      float* __restrict__ out) {
    __shared__ float a0s[FDIM], a1s[FDIM], fe[FDIM];
    __shared__ float hid[256];
    const int b = blockIdx.x, t = threadIdx.x;
    const int n = gsi[b];
    const int wv = t >> 6, lane = t & 63;
    if (wv < 2) {
        const int j = idx2[n];
        const int rb = wv * (N1_CAP + 1);
        float v[12];
        att_accum(fsd, idx2, j, lane, wv ? attn1 : attn0,
                  rowpa[rb + j], rowpa[rb + j + 1],
                  eida + (size_t)wv * NE, wv ? src1 : src0,
                  wv ? 768 : 0, wv ? 2304 : 1536, v);
        float* dl = wv ? a1s : a0s;
#pragma unroll
        for (int q = 0; q < 12; ++q) dl[lane * 12 + q] = v[q];
    }
    __syncthreads();
    for (int d = t; d < FDIM; d += 256)
        fe[d] = u2f(__bfloat16_as_ushort(h[(size_t)n * FDIM + d])) + a0s[d] + a1s[d];
    __syncthreads();
    float acc = fc1b[t];
    for (int k = 0; k < FDIM; ++k) acc += fe[k] * fc1w[k * 256 + t];
    hid[t] = (acc > 0.f) ? acc : 0.f;
    __syncthreads();
    if (t < NC) {
        float a2 = fc2b[t];
        for (int k = 0; k < 256; ++k) a2 += hid[k] * fc2w[k * NC + t];
        astore_f(&out[1 + b * NC + t], a2);
    }

    __syncthreads();
    __shared__ int amlast;
    if (t == 0) amlast = (atomicAdd(&cnts[9], 1) == NB - 1) ? 1 : 0;
    __syncthreads();
    if (amlast) {
        __shared__ float red[256];
        float m = -INFINITY;
        float lg[NC];
#pragma unroll
        for (int c = 0; c < NC; ++c) {
            lg[c] = aload_f(&out[1 + t * NC + c]);
            m = fmaxf(m, lg[c]);
        }
        float sum = 0.f;
#pragma unroll
        for (int c = 0; c < NC; ++c) sum += expf(lg[c] - m);
        const float lse = m + logf(sum);
        const float ll = lg[labels[t]];
        red[t] = lse - ll;
        __syncthreads();
        for (int s = 128; s > 0; s >>= 1) {
            if (t < s) red[t] += red[t + s];
            __syncthreads();
        }
        if (t == 0) out[0] = red[0] / (float)NB;
    }
}

extern "C" void kernel_launch(void* const* d_in, const int* in_sizes, int n_in,
                              void* d_out, int out_size, void* d_ws, size_t ws_size,
                              hipStream_t stream) {
    const float* feats = (const float*)d_in[0];
    const int* src0    = (const int*)d_in[15];
    const int* dst0    = (const int*)d_in[16];
    const int* src1    = (const int*)d_in[17];
    const int* dst1    = (const int*)d_in[18];
    const int* gsi     = (const int*)d_in[19];
    const int* labels  = (const int*)d_in[20];

    const size_t NF = (size_t)N_NODES * FDIM;
    const size_t WSZ = (size_t)FDIM * FDIM;
    char* p = (char*)d_ws;
    bf16* h    = (bf16*)p;  p += NF * 2;
    bf16* fsd  = (bf16*)p;  p += (size_t)A1_CAP * NFUSE * 2;
    bf16* WtFl = (bf16*)p;  p += 8 * WSZ * 2;
    float* pb  = (float*)p; p += 2 * NFUSE * 4;
    // contiguous zero region
    int* fA1  = (int*)p;    p += (size_t)N_NODES * 4;
    int* fL1  = (int*)p;    p += (size_t)N_NODES * 4;
    int* cnts = (int*)p;    p += 64 * 4;
    int* dega = (int*)p;    p += 2 * (size_t)N1_CAP * 4;
    int* idx1  = (int*)p;   p += (size_t)N_NODES * 4;
    int* idx2  = (int*)p;   p += (size_t)N_NODES * 4;
    int* list1 = (int*)p;   p += (size_t)A1_CAP * 4;
    int* list2 = (int*)p;   p += (size_t)N1_CAP * 4;
    int* list0 = (int*)p;   p += 256 * 4;
    int* rowpa = (int*)p;   p += 2 * ((size_t)N1_CAP + 1) * 4;
    int* cursora = (int*)p; p += 2 * (size_t)N1_CAP * 4;
    int* eida  = (int*)p;   p += 2 * (size_t)NE * 4;

    // 1. zero flags/cnts/dega
    zero_kernel<<<(ZERO_INTS / 4 + 255) / 256, 256, 0, stream>>>((int4*)fA1);
    // 2. markA (plain-store marks + list0)
    markA_kernel<<<1 + SCT, 256, 0, stream>>>(gsi, src0, dst0, src1, dst1,
                                              fL1, fA1, list0, cnts);
    // 3. markB
    markB_kernel<<<dim3(EB, 2), 256, 0, stream>>>(src0, dst0, src1, dst1, fL1, fA1);
    // 4. compact
    compact_kernel<<<NBLK, 256, 0, stream>>>(fA1, fL1, list1, idx1, list2, idx2, cnts);
    // 5. setup: twt | bias | cvt | hist (wide, overlapping)
    setup_kernel<<<SETUPH_BLOCKS, 256, 0, stream>>>(
        (const float*)d_in[1], (const float*)d_in[3], (const float*)d_in[6], (const float*)d_in[8],
        (const float*)d_in[2], (const float*)d_in[4], (const float*)d_in[7], (const float*)d_in[9],
        feats, list1, &cnts[0], WtFl, pb, h, dst0, dst1, fL1, idx2, dega);
    // 6. active scan
    scana_kernel<<<1, 256, 0, stream>>>(dega, rowpa, cursora);
    // 7. active scatter
    scattera_kernel<<<dim3(EB, 2), 256, 0, stream>>>(dst0, dst1, fL1, idx2, cursora, eida);

    const int blocksA0 = (A1_CAP / 128) * GTN;
    const int blocksB0 = (N1_CAP / 128) * GTN;
    const int blocksA1 = (N1_CAP / 128) * GTN;
    const int blocksB1 = (256 / 128) * GTN;

    // 8. layer-0 GEMM
    gemm2<<<blocksA0 + blocksB0, 256, 0, stream>>>(
        h, WtFl, pb, fsd,
        list1, &cnts[0], A1_CAP, list2, &cnts[1], N1_CAP, idx1, blocksA0);
    // 9. layer-0 agg
    aggL_kernel<<<(N1_CAP + 3) / 4, 256, 0, stream>>>(
        fsd, idx1, (const float*)d_in[5], (const float*)d_in[10],
        rowpa, eida, src0, src1, h, list2, &cnts[1]);
    // 10. layer-1 GEMM
    gemm2<<<blocksA1 + blocksB1, 256, 0, stream>>>(
        h, WtFl + 4 * WSZ, pb + NFUSE, fsd,
        list2, &cnts[1], N1_CAP, list0, &cnts[2], 256, idx2, blocksA1);
    // 11. layer-1 agg + head + last-block loss
    agghead_kernel<<<NB, 256, 0, stream>>>(
        fsd, idx2, (const float*)d_in[5] + FDIM, (const float*)d_in[10] + FDIM,
        rowpa, eida, src0, src1, h, gsi,
        (const float*)d_in[11], (const float*)d_in[12],
        (const float*)d_in[13], (const float*)d_in[14],
        labels, cnts, (float*)d_out);
}